// Round 10
// baseline (376.000 us; speedup 1.0000x reference)
//
#include <hip/hip_runtime.h>
#include <math.h>

// EdgeConv: B=4, C=64, N=32768, k=16, O=64
// U = (W1[:,:64]-W1[:,64:]) @ x + b1 ; V = W1[:,64:] @ x   (bf16-stored)
// h1 = U[n] + V[idx[n,k]] ; BN1 folded: relu(a1*h+c1) = a1*relu(h+c1/a1) (a1>0),
// a1 folded into W2 B-frags. Layer2 via bf16 MFMA 16x16x32 (16 neighbors = rows).
// XCD swizzle: batch b -> XCD pair {2b,2b+1} so V (4MB bf16/batch) stays L2-resident.
// R9: NON-TEMPORAL loads/stores for streaming data (U, idx, Mx, out) so streams
// don't evict the V hot set (R7/R8's ~507MB fetch = L2 thrash cliff at occ 40%).
// (R8 compile fix: nt builtins need ext_vector types, not HIP_vector_type.)

#define EPSV 1e-5f
constexpr int Cc = 64;
constexpr int Nn = 32768;
constexpr int BN = 131072;                     // B*N
constexpr float TOTF = 2097152.0f;             // B*N*k

typedef __attribute__((ext_vector_type(8))) short short8;
typedef __attribute__((ext_vector_type(8))) unsigned short ushort8;
typedef __attribute__((ext_vector_type(4))) unsigned short ushortx4;
typedef __attribute__((ext_vector_type(4))) float floatx4;

#define WAITV(N) asm volatile("s_waitcnt vmcnt(" #N ")" ::: "memory")

__device__ __forceinline__ unsigned short f2bf(float f) {
  __bf16 b = (__bf16)f;
  return __builtin_bit_cast(unsigned short, b);
}
__device__ __forceinline__ short f2bfs(float f) {
  __bf16 b = (__bf16)f;
  return __builtin_bit_cast(short, b);
}
__device__ __forceinline__ float bf2f(unsigned short u) {
  union { unsigned u; float f; } x; x.u = ((unsigned)u) << 16; return x.f;
}
__device__ __forceinline__ void gload_lds16(const void* g, void* l) {
  __builtin_amdgcn_global_load_lds(
      (const __attribute__((address_space(1))) unsigned int*)g,
      (__attribute__((address_space(3))) unsigned int*)l, 16, 0, 0);
}
__device__ __forceinline__ ushort8 ntld8(const unsigned short* p) {
  return __builtin_nontemporal_load((const ushort8*)p);
}
// blockIdx -> (batch, 64-point chunk): batch pinned to XCD pair (bid%8)>>1
__device__ __forceinline__ void swz(int p, int& b, int& n0) {
  b = (p & 7) >> 1;
  n0 = (((p >> 3) << 1) | (p & 1)) << 6;
}

// ---------------- K1: U,V precompute (f32 compute, bf16 store) ----------------
__global__ __launch_bounds__(256) void k_uv(const float* __restrict__ x,
                                            const float* __restrict__ W1,
                                            const float* __restrict__ b1,
                                            unsigned short* __restrict__ Ub,
                                            unsigned short* __restrict__ Vb) {
  __shared__ __align__(16) float wdT[64][64];
  __shared__ __align__(16) float wbT[64][64];
  __shared__ __align__(16) float xs[64][64];
  int t = threadIdx.x;
  int b, n0; swz(blockIdx.x, b, n0);

  for (int i = t; i < 4096; i += 256) {
    int o = i & 63, c = i >> 6;
    float wa = W1[o * 128 + c];
    float wb = W1[o * 128 + 64 + c];
    wdT[c][o] = wa - wb;
    wbT[c][o] = wb;
  }
  const float* xb = x + (size_t)b * Cc * Nn + n0;
  for (int i = t; i < 4096; i += 256) {
    int c = i >> 6, p = i & 63;
    xs[c][p] = __builtin_nontemporal_load(&xb[(size_t)c * Nn + p]);
  }
  __syncthreads();

  int lane = t & 63;
  int pg = t >> 6;
  int pbase = pg * 16;
  float bv = b1[lane];
  float u[16], v[16];
#pragma unroll
  for (int j = 0; j < 16; ++j) { u[j] = bv; v[j] = 0.f; }

  for (int c = 0; c < 64; ++c) {
    float wd = wdT[c][lane];
    float wb = wbT[c][lane];
#pragma unroll
    for (int j4 = 0; j4 < 4; ++j4) {
      float4 xq = *(const float4*)&xs[c][pbase + j4 * 4];
      u[j4 * 4 + 0] += wd * xq.x; v[j4 * 4 + 0] += wb * xq.x;
      u[j4 * 4 + 1] += wd * xq.y; v[j4 * 4 + 1] += wb * xq.y;
      u[j4 * 4 + 2] += wd * xq.z; v[j4 * 4 + 2] += wb * xq.z;
      u[j4 * 4 + 3] += wd * xq.w; v[j4 * 4 + 3] += wb * xq.w;
    }
  }
  size_t base = ((size_t)b * Nn + n0 + pbase) * 64 + lane;
#pragma unroll
  for (int j = 0; j < 16; ++j) {
    __builtin_nontemporal_store(f2bf(u[j]), &Ub[base + (size_t)j * 64]);
    Vb[base + (size_t)j * 64] = f2bf(v[j]);   // normal: warm L2 for the gathers
  }
}

// ---------------- K2: BN1 stats, async-gather, 3-deep ----------------
__global__ __launch_bounds__(256, 4) void k_stats1(const unsigned short* __restrict__ Ub,
                                                   const unsigned short* __restrict__ Vb,
                                                   const int* __restrict__ idx,
                                                   float* __restrict__ s1g,
                                                   float* __restrict__ q1g) {
  __shared__ int idx_s[1024];
  __shared__ __align__(16) unsigned short vstage[4][4][1024];  // 32 KB
  __shared__ float rs[4][64], rq[4][64];
  int t = threadIdx.x;
  int l = t & 63, w = t >> 6;
  int g = l >> 4, r = l & 15;
  int b, n0; swz(blockIdx.x, b, n0);
  size_t bbase = (size_t)b * Nn, bn0 = bbase + n0, wbn = bn0 + w * 16;
  int g8 = g * 8;
  {
    const int* ip = idx + bn0 * 16;
    for (int i = t; i < 1024; i += 256) idx_s[i] = __builtin_nontemporal_load(&ip[i]);
  }
  __syncthreads();
  const unsigned short* Vbb = Vb + (bbase << 6);

  auto STAGE = [&](int pt, int slot) {
    int jn = idx_s[(w * 16 + pt) * 16 + r];
    const unsigned short* vp = Vbb + ((size_t)jn << 6) + g8;
    unsigned short* sl = &vstage[w][slot][0];
    gload_lds16(vp, sl);
    gload_lds16(vp + 32, sl + 512);
  };
  auto LOADU = [&](int pt, ushort8& lo, ushort8& hi) {
    const unsigned short* up = Ub + ((wbn + pt) << 6);
    lo = ntld8(up + g8);
    hi = ntld8(up + 32 + g8);
  };

  ushort8 uA_lo, uA_hi, uB_lo, uB_hi;
  STAGE(0, 0); STAGE(1, 1); STAGE(2, 2); LOADU(0, uA_lo, uA_hi);
  float s[16], q[16];
#pragma unroll
  for (int i = 0; i < 16; ++i) { s[i] = 0.f; q[i] = 0.f; }

  // ledger (ops, 2 per S/U): steady W=4; b0=4; b13=2; b14=2; b15=0
#define S1BODY(PT, PTI, DOST, DOLU, VMC) { \
    if (DOST) STAGE((PT) + 3, ((PTI) + 3) & 3); \
    if (DOLU) { if (((PTI) + 1) & 1) LOADU((PT) + 1, uB_lo, uB_hi); \
                else                 LOADU((PT) + 1, uA_lo, uA_hi); } \
    WAITV(VMC); \
    const unsigned short* sl = &vstage[w][(PTI)][0]; \
    ushort8 vlo = *(const ushort8*)(sl + l * 8); \
    ushort8 vhi = *(const ushort8*)(sl + 512 + l * 8); \
    ushort8 ulo = ((PTI) & 1) ? uB_lo : uA_lo; \
    ushort8 uhi = ((PTI) & 1) ? uB_hi : uA_hi; \
    _Pragma("unroll") \
    for (int i = 0; i < 8; ++i) { \
      float h0 = bf2f(ulo[i]) + bf2f(vlo[i]); \
      float h1 = bf2f(uhi[i]) + bf2f(vhi[i]); \
      s[i] += h0; q[i] += h0 * h0; \
      s[8 + i] += h1; q[8 + i] += h1 * h1; \
    } }

  S1BODY(0, 0, 1, 1, 4);
  S1BODY(1, 1, 1, 1, 4);
  S1BODY(2, 2, 1, 1, 4);
  S1BODY(3, 3, 1, 1, 4);
#pragma unroll 1
  for (int ptg = 1; ptg < 3; ++ptg) {
    int p0 = ptg * 4;
    S1BODY(p0 + 0, 0, 1, 1, 4);
    S1BODY(p0 + 1, 1, 1, 1, 4);
    S1BODY(p0 + 2, 2, 1, 1, 4);
    S1BODY(p0 + 3, 3, 1, 1, 4);
  }
  S1BODY(12, 0, 1, 1, 4);
  S1BODY(13, 1, 0, 1, 2);
  S1BODY(14, 2, 0, 1, 2);
  S1BODY(15, 3, 0, 0, 0);
#undef S1BODY

  // per-wave reduce via LDS transpose (reuse this wave's vstage area)
  float* scr = (float*)&vstage[w][0][0];
  int gg = (l & 31) >> 3, ii = (l & 7) | ((l >> 5) << 3);
  *(floatx4*)&scr[l * 16 + 0]  = (floatx4){s[0], s[1], s[2], s[3]};
  *(floatx4*)&scr[l * 16 + 4]  = (floatx4){s[4], s[5], s[6], s[7]};
  *(floatx4*)&scr[l * 16 + 8]  = (floatx4){s[8], s[9], s[10], s[11]};
  *(floatx4*)&scr[l * 16 + 12] = (floatx4){s[12], s[13], s[14], s[15]};
  asm volatile("s_waitcnt lgkmcnt(0)" ::: "memory");
  float sc = 0.f;
#pragma unroll
  for (int rr = 0; rr < 16; ++rr) sc += scr[(gg * 16 + rr) * 16 + ii];
  asm volatile("s_waitcnt lgkmcnt(0)" ::: "memory");
  *(floatx4*)&scr[l * 16 + 0]  = (floatx4){q[0], q[1], q[2], q[3]};
  *(floatx4*)&scr[l * 16 + 4]  = (floatx4){q[4], q[5], q[6], q[7]};
  *(floatx4*)&scr[l * 16 + 8]  = (floatx4){q[8], q[9], q[10], q[11]};
  *(floatx4*)&scr[l * 16 + 12] = (floatx4){q[12], q[13], q[14], q[15]};
  asm volatile("s_waitcnt lgkmcnt(0)" ::: "memory");
  float qc = 0.f;
#pragma unroll
  for (int rr = 0; rr < 16; ++rr) qc += scr[(gg * 16 + rr) * 16 + ii];
  rs[w][l] = sc; rq[w][l] = qc;
  __syncthreads();
  if (w == 0) {
    float ss = rs[0][l] + rs[1][l] + rs[2][l] + rs[3][l];
    float qq = rq[0][l] + rq[1][l] + rq[2][l] + rq[3][l];
    atomicAdd(&s1g[l], ss);
    atomicAdd(&q1g[l], qq);
  }
}

// ---------------- finalize BN stats -> affine (+ c/a) ----------------
__global__ void k_fin(const float* __restrict__ s, const float* __restrict__ q,
                      const float* __restrict__ g, const float* __restrict__ be,
                      float* __restrict__ a, float* __restrict__ c,
                      float* __restrict__ ca) {
  int o = threadIdx.x;
  float mean = s[o] / TOTF;
  float var = q[o] / TOTF - mean * mean;
  float av = g[o] / sqrtf(var + EPSV);
  float cv = be[o] - mean * av;
  a[o] = av;
  c[o] = cv;
  ca[o] = cv / av;
}

// -------- K4: async-gather -> relu1 -> MFMA(W2*a1) -> {BN2 stats, max->Mxb} --------
__global__ __launch_bounds__(256, 4) void k_main(const unsigned short* __restrict__ Ub,
                                                 const unsigned short* __restrict__ Vb,
                                                 const int* __restrict__ idx,
                                                 const float* __restrict__ a1,
                                                 const float* __restrict__ c1a,
                                                 const float* __restrict__ W2,
                                                 const float* __restrict__ b2,
                                                 float* __restrict__ s2,
                                                 float* __restrict__ q2,
                                                 unsigned short* __restrict__ Mxb) {
  __shared__ int idx_s[1024];
  __shared__ __align__(16) unsigned short vstage[4][4][1024];  // 32 KB
  __shared__ float sred[4][64], qred[4][64];
  int t = threadIdx.x;
  int l = t & 63, w = t >> 6;
  int g = l >> 4, r = l & 15;
  int b, n0; swz(blockIdx.x, b, n0);
  size_t bbase = (size_t)b * Nn, bn0 = bbase + n0, wbn = bn0 + w * 16;
  int g8 = g * 8;
  {
    const int* ip = idx + bn0 * 16;
    for (int i = t; i < 1024; i += 256) idx_s[i] = __builtin_nontemporal_load(&ip[i]);
  }

  // B-frags: W2*a1, B[k=o][col=p]; lane: col=r, k=32hh+8g+i
  short8 bw[4][2];
#pragma unroll
  for (int tp = 0; tp < 4; ++tp)
#pragma unroll
    for (int hh = 0; hh < 2; ++hh)
#pragma unroll
      for (int i = 0; i < 8; ++i) {
        int o = 32 * hh + 8 * g + i;
        bw[tp][hh][i] = f2bfs(W2[(16 * tp + r) * 64 + o] * a1[o]);
      }
  float c1av[16];
#pragma unroll
  for (int i = 0; i < 8; ++i) {
    c1av[i] = c1a[g8 + i];
    c1av[8 + i] = c1a[32 + g8 + i];
  }
  float b2t[4];
#pragma unroll
  for (int tp = 0; tp < 4; ++tp) b2t[tp] = b2[16 * tp + r];

  __syncthreads();
  const unsigned short* Vbb = Vb + (bbase << 6);

  auto STAGE = [&](int pt, int slot) {
    int jn = idx_s[(w * 16 + pt) * 16 + r];
    const unsigned short* vp = Vbb + ((size_t)jn << 6) + g8;
    unsigned short* sl = &vstage[w][slot][0];
    gload_lds16(vp, sl);
    gload_lds16(vp + 32, sl + 512);
  };
  auto LOADU = [&](int pt, ushort8& lo, ushort8& hi) {
    const unsigned short* up = Ub + ((wbn + pt) << 6);
    lo = ntld8(up + g8);
    hi = ntld8(up + 32 + g8);
  };

  ushort8 uA_lo, uA_hi, uB_lo, uB_hi;
  STAGE(0, 0); STAGE(1, 1); STAGE(2, 2); LOADU(0, uA_lo, uA_hi);
  float sa[4] = {0.f, 0.f, 0.f, 0.f}, qa[4] = {0.f, 0.f, 0.f, 0.f};

  // ledger (stores count in vmcnt): b0=4, steady=5, b13=3, b14=3, b15=1
#define MBODY(PT, PTI, DOST, DOLU, VMC) { \
    if (DOST) STAGE((PT) + 3, ((PTI) + 3) & 3); \
    if (DOLU) { if (((PTI) + 1) & 1) LOADU((PT) + 1, uB_lo, uB_hi); \
                else                 LOADU((PT) + 1, uA_lo, uA_hi); } \
    WAITV(VMC); \
    const unsigned short* sl = &vstage[w][(PTI)][0]; \
    ushort8 vlo = *(const ushort8*)(sl + l * 8); \
    ushort8 vhi = *(const ushort8*)(sl + 512 + l * 8); \
    ushort8 ulo = ((PTI) & 1) ? uB_lo : uA_lo; \
    ushort8 uhi = ((PTI) & 1) ? uB_hi : uA_hi; \
    float h[16]; \
    _Pragma("unroll") \
    for (int i = 0; i < 8; ++i) { \
      h[i] = bf2f(ulo[i]) + bf2f(vlo[i]); \
      h[8 + i] = bf2f(uhi[i]) + bf2f(vhi[i]); \
    } \
    _Pragma("unroll") \
    for (int i = 0; i < 16; ++i) h[i] = fmaxf(h[i] + c1av[i], 0.f); \
    short8 fa0, fa1; \
    _Pragma("unroll") \
    for (int i = 0; i < 8; ++i) { fa0[i] = f2bfs(h[i]); fa1[i] = f2bfs(h[8 + i]); } \
    float m0 = -3.4e38f, m1 = -3.4e38f, m2 = -3.4e38f, m3 = -3.4e38f; \
    _Pragma("unroll") \
    for (int tp = 0; tp < 4; ++tp) { \
      floatx4 acc = {b2t[tp], b2t[tp], b2t[tp], b2t[tp]}; \
      acc = __builtin_amdgcn_mfma_f32_16x16x32_bf16(fa0, bw[tp][0], acc, 0, 0, 0); \
      acc = __builtin_amdgcn_mfma_f32_16x16x32_bf16(fa1, bw[tp][1], acc, 0, 0, 0); \
      float mm = -3.4e38f; \
      _Pragma("unroll") \
      for (int rg = 0; rg < 4; ++rg) { \
        float h2 = acc[rg]; \
        sa[tp] += h2; qa[tp] += h2 * h2; \
        mm = fmaxf(mm, h2); \
      } \
      mm = fmaxf(mm, __shfl_xor(mm, 16)); \
      mm = fmaxf(mm, __shfl_xor(mm, 32)); \
      if (tp == 0) m0 = mm; else if (tp == 1) m1 = mm; \
      else if (tp == 2) m2 = mm; else m3 = mm; \
    } \
    float mv = (g == 0) ? m0 : (g == 1) ? m1 : (g == 2) ? m2 : m3; \
    __builtin_nontemporal_store(f2bf(mv), &Mxb[((wbn + (PT)) << 6) + l]); }

  MBODY(0, 0, 1, 1, 4);
  MBODY(1, 1, 1, 1, 5);
  MBODY(2, 2, 1, 1, 5);
  MBODY(3, 3, 1, 1, 5);
#pragma unroll 1
  for (int ptg = 1; ptg < 3; ++ptg) {
    int p0 = ptg * 4;
    MBODY(p0 + 0, 0, 1, 1, 5);
    MBODY(p0 + 1, 1, 1, 1, 5);
    MBODY(p0 + 2, 2, 1, 1, 5);
    MBODY(p0 + 3, 3, 1, 1, 5);
  }
  MBODY(12, 0, 1, 1, 5);
  MBODY(13, 1, 0, 1, 3);
  MBODY(14, 2, 0, 1, 3);
  MBODY(15, 3, 0, 0, 1);
#undef MBODY

  // stats reduce: over g (shfl), waves (LDS), then atomic
#pragma unroll
  for (int tp = 0; tp < 4; ++tp) {
    sa[tp] += __shfl_xor(sa[tp], 16); sa[tp] += __shfl_xor(sa[tp], 32);
    qa[tp] += __shfl_xor(qa[tp], 16); qa[tp] += __shfl_xor(qa[tp], 32);
  }
  if (g == 0) {
#pragma unroll
    for (int tp = 0; tp < 4; ++tp) { sred[w][tp * 16 + r] = sa[tp]; qred[w][tp * 16 + r] = qa[tp]; }
  }
  __syncthreads();
  if (w == 0) {
    float ss = sred[0][l] + sred[1][l] + sred[2][l] + sred[3][l];
    float qq = qred[0][l] + qred[1][l] + qred[2][l] + qred[3][l];
    atomicAdd(&s2[l], ss);
    atomicAdd(&q2[l], qq);
  }
}

// -------- K6: BN2+relu on Mxb (point-major bf16), transposed write --------
__global__ __launch_bounds__(256) void k_out(const unsigned short* __restrict__ Mxb,
                                             const float* __restrict__ a2,
                                             const float* __restrict__ c2,
                                             float* __restrict__ out) {
  __shared__ float om[64][65];
  __shared__ float a2s[64], c2s[64];
  int t = threadIdx.x;
  int b, n0; swz(blockIdx.x, b, n0);
  if (t < 64) { a2s[t] = a2[t]; c2s[t] = c2[t]; }
  __syncthreads();
  const ushortx4* src = (const ushortx4*)(Mxb + ((size_t)b * Nn + n0) * 64);
  for (int i = t; i < 1024; i += 256) {
    ushortx4 v4 = __builtin_nontemporal_load(&src[i]);
    int ptl = i >> 4, p0 = (i & 15) * 4;
#pragma unroll
    for (int j = 0; j < 4; ++j) {
      int p = p0 + j;
      om[p][ptl] = fmaxf(fmaf(a2s[p], bf2f(v4[j]), c2s[p]), 0.f);
    }
  }
  __syncthreads();
  for (int i = t; i < 1024; i += 256) {
    int p = i >> 4, nn4 = (i & 15) * 4;
    floatx4 o4 = {om[p][nn4], om[p][nn4 + 1], om[p][nn4 + 2], om[p][nn4 + 3]};
    __builtin_nontemporal_store(o4, (floatx4*)&out[((size_t)b * 64 + p) * Nn + n0 + nn4]);
  }
}

extern "C" void kernel_launch(void* const* d_in, const int* in_sizes, int n_in,
                              void* d_out, int out_size, void* d_ws, size_t ws_size,
                              hipStream_t stream) {
  const float* x   = (const float*)d_in[0];
  const int*   idx = (const int*)d_in[1];
  const float* W1  = (const float*)d_in[2];
  const float* b1  = (const float*)d_in[3];
  const float* g1  = (const float*)d_in[4];
  const float* be1 = (const float*)d_in[5];
  const float* W2  = (const float*)d_in[6];
  const float* b2  = (const float*)d_in[7];
  const float* g2  = (const float*)d_in[8];
  const float* be2 = (const float*)d_in[9];
  float* out = (float*)d_out;

  unsigned short* Ub = (unsigned short*)d_ws;        // 16 MB
  unsigned short* Vb = Ub + (size_t)BN * 64;         // 16 MB
  float* st = (float*)(Vb + (size_t)BN * 64);
  float* s1  = st,       *q1 = st + 64,  *a1 = st + 128, *c1 = st + 192;
  float* s2  = st + 256, *q2 = st + 320, *a2 = st + 384, *c2 = st + 448;
  float* c1a = st + 512, *c2a = st + 576;
  unsigned short* Mxb = (unsigned short*)(st + 640); // 16 MB, [b][n][ch]

  hipError_t e = hipMemsetAsync(st, 0, 512 * sizeof(float), stream); (void)e;
  k_uv<<<2048, 256, 0, stream>>>(x, W1, b1, Ub, Vb);
  k_stats1<<<2048, 256, 0, stream>>>(Ub, Vb, idx, s1, q1);
  k_fin<<<1, 64, 0, stream>>>(s1, q1, g1, be1, a1, c1, c1a);
  k_main<<<2048, 256, 0, stream>>>(Ub, Vb, idx, a1, c1a, W2, b2, s2, q2, Mxb);
  k_fin<<<1, 64, 0, stream>>>(s2, q2, g2, be2, a2, c2, c2a);
  k_out<<<2048, 256, 0, stream>>>(Mxb, a2, c2, out);
}

// Round 11
// 322.244 us; speedup vs baseline: 1.1668x; 1.1668x over previous
//
#include <hip/hip_runtime.h>
#include <math.h>

// EdgeConv: B=4, C=64, N=32768, k=16, O=64
// U = (W1[:,:64]-W1[:,64:]) @ x + b1 ; V = W1[:,64:] @ x   (bf16-stored)
// h1 = U[n] + V[idx[n,k]] ; BN1 folded: relu(a1*h+c1) = a1*relu(h+c1/a1) (a1>0),
// a1 folded into W2 B-frags. Layer2 via bf16 MFMA 16x16x32 (16 neighbors = rows).
// XCD swizzle: batch b -> XCD pair {2b,2b+1} so V (4MB bf16/batch) stays L2-resident.
// R10: R5 config (best measured: k_main 96.8us, FETCH 49MB) + LDS pad to force
// 2 blocks/CU. Evidence: occ 27% -> FETCH 49MB; occ 40% -> 505MB (L2 thrash
// cliff; store layout and nt flags both ruled out as causes).

#define EPSV 1e-5f
constexpr int Cc = 64;
constexpr int Nn = 32768;
constexpr int BN = 131072;                     // B*N
constexpr float TOTF = 2097152.0f;             // B*N*k

typedef __attribute__((ext_vector_type(8))) short short8;
typedef __attribute__((ext_vector_type(8))) unsigned short ushort8;
typedef __attribute__((ext_vector_type(4))) float floatx4;

#define WAITV(N) asm volatile("s_waitcnt vmcnt(" #N ")" ::: "memory")

__device__ __forceinline__ unsigned short f2bf(float f) {
  __bf16 b = (__bf16)f;
  return __builtin_bit_cast(unsigned short, b);
}
__device__ __forceinline__ short f2bfs(float f) {
  __bf16 b = (__bf16)f;
  return __builtin_bit_cast(short, b);
}
__device__ __forceinline__ float bf2f(unsigned short u) {
  union { unsigned u; float f; } x; x.u = ((unsigned)u) << 16; return x.f;
}
__device__ __forceinline__ void gload_lds16(const void* g, void* l) {
  __builtin_amdgcn_global_load_lds(
      (const __attribute__((address_space(1))) unsigned int*)g,
      (__attribute__((address_space(3))) unsigned int*)l, 16, 0, 0);
}
// blockIdx -> (batch, 64-point chunk): batch pinned to XCD pair (bid%8)>>1
__device__ __forceinline__ void swz(int p, int& b, int& n0) {
  b = (p & 7) >> 1;
  n0 = (((p >> 3) << 1) | (p & 1)) << 6;
}

// ---------------- K1: U,V precompute (f32 compute, bf16 store) ----------------
__global__ __launch_bounds__(256) void k_uv(const float* __restrict__ x,
                                            const float* __restrict__ W1,
                                            const float* __restrict__ b1,
                                            unsigned short* __restrict__ Ub,
                                            unsigned short* __restrict__ Vb) {
  __shared__ __align__(16) float wdT[64][64];
  __shared__ __align__(16) float wbT[64][64];
  __shared__ __align__(16) float xs[64][64];
  int t = threadIdx.x;
  int b, n0; swz(blockIdx.x, b, n0);

  for (int i = t; i < 4096; i += 256) {
    int o = i & 63, c = i >> 6;
    float wa = W1[o * 128 + c];
    float wb = W1[o * 128 + 64 + c];
    wdT[c][o] = wa - wb;
    wbT[c][o] = wb;
  }
  const float* xb = x + (size_t)b * Cc * Nn + n0;
  for (int i = t; i < 4096; i += 256) {
    int c = i >> 6, p = i & 63;
    xs[c][p] = xb[(size_t)c * Nn + p];
  }
  __syncthreads();

  int lane = t & 63;
  int pg = t >> 6;
  int pbase = pg * 16;
  float bv = b1[lane];
  float u[16], v[16];
#pragma unroll
  for (int j = 0; j < 16; ++j) { u[j] = bv; v[j] = 0.f; }

  for (int c = 0; c < 64; ++c) {
    float wd = wdT[c][lane];
    float wb = wbT[c][lane];
#pragma unroll
    for (int j4 = 0; j4 < 4; ++j4) {
      float4 xq = *(const float4*)&xs[c][pbase + j4 * 4];
      u[j4 * 4 + 0] += wd * xq.x; v[j4 * 4 + 0] += wb * xq.x;
      u[j4 * 4 + 1] += wd * xq.y; v[j4 * 4 + 1] += wb * xq.y;
      u[j4 * 4 + 2] += wd * xq.z; v[j4 * 4 + 2] += wb * xq.z;
      u[j4 * 4 + 3] += wd * xq.w; v[j4 * 4 + 3] += wb * xq.w;
    }
  }
  size_t base = ((size_t)b * Nn + n0 + pbase) * 64 + lane;
#pragma unroll
  for (int j = 0; j < 16; ++j) {
    Ub[base + (size_t)j * 64] = f2bf(u[j]);
    Vb[base + (size_t)j * 64] = f2bf(v[j]);
  }
}

// ---------------- K2: BN1 stats, async-gather pipeline ----------------
__global__ __launch_bounds__(256) void k_stats1(const unsigned short* __restrict__ Ub,
                                                const unsigned short* __restrict__ Vb,
                                                const int* __restrict__ idx,
                                                float* __restrict__ s1g,
                                                float* __restrict__ q1g) {
  __shared__ int idx_s[1024];
  __shared__ __align__(16) unsigned short vstage[4][3][1024];
  __shared__ float rs[4][64], rq[4][64];
  __shared__ __align__(16) unsigned char lds_pad[26624];  // cap 2 blocks/CU
  int t = threadIdx.x;
  if (blockIdx.x > 0x7FFFFFF0u) ((volatile unsigned char*)lds_pad)[t] = 1;
  int l = t & 63, w = t >> 6;
  int g = l >> 4, r = l & 15;
  int b, n0; swz(blockIdx.x, b, n0);
  size_t bbase = (size_t)b * Nn, bn0 = bbase + n0, wbn = bn0 + w * 16;
  int g8 = g * 8;
  {
    const int* ip = idx + bn0 * 16;
    for (int i = t; i < 1024; i += 256) idx_s[i] = ip[i];
  }
  __syncthreads();
  const unsigned short* Vbb = Vb + (bbase << 6);

  auto STAGE = [&](int pt, int slot) {
    int jn = idx_s[(w * 16 + pt) * 16 + r];
    const unsigned short* vp = Vbb + ((size_t)jn << 6) + g8;
    unsigned short* sl = &vstage[w][slot][0];
    gload_lds16(vp, sl);
    gload_lds16(vp + 32, sl + 512);
  };
  auto LOADU = [&](int pt, ushort8& lo, ushort8& hi) {
    const unsigned short* up = Ub + ((wbn + pt) << 6);
    lo = *(const ushort8*)(up + g8);
    hi = *(const ushort8*)(up + 32 + g8);
  };

  ushort8 uA_lo, uA_hi, uB_lo, uB_hi;
  STAGE(0, 0); LOADU(0, uA_lo, uA_hi); STAGE(1, 1);
  float s[16], q[16];
#pragma unroll
  for (int i = 0; i < 16; ++i) { s[i] = 0.f; q[i] = 0.f; }

#define S1BODY(PT, DOLU, DOST, WAIT) { \
    if (DOLU) { if ((PT) & 1) LOADU((PT) + 1, uA_lo, uA_hi); else LOADU((PT) + 1, uB_lo, uB_hi); } \
    if (DOST) STAGE((PT) + 2, ((PT) + 2) % 3); \
    WAIT; \
    const unsigned short* sl = &vstage[w][(PT) % 3][0]; \
    ushort8 vlo = *(const ushort8*)(sl + l * 8); \
    ushort8 vhi = *(const ushort8*)(sl + 512 + l * 8); \
    ushort8 ulo = ((PT) & 1) ? uB_lo : uA_lo; \
    ushort8 uhi = ((PT) & 1) ? uB_hi : uA_hi; \
    _Pragma("unroll") \
    for (int i = 0; i < 8; ++i) { \
      float h0 = bf2f(ulo[i]) + bf2f(vlo[i]); \
      float h1 = bf2f(uhi[i]) + bf2f(vhi[i]); \
      s[i] += h0; q[i] += h0 * h0; \
      s[8 + i] += h1; q[8 + i] += h1 * h1; \
    } }

  S1BODY(0, 1, 1, WAITV(6));  S1BODY(1, 1, 1, WAITV(6));
  S1BODY(2, 1, 1, WAITV(6));  S1BODY(3, 1, 1, WAITV(6));
  S1BODY(4, 1, 1, WAITV(6));  S1BODY(5, 1, 1, WAITV(6));
  S1BODY(6, 1, 1, WAITV(6));  S1BODY(7, 1, 1, WAITV(6));
  S1BODY(8, 1, 1, WAITV(6));  S1BODY(9, 1, 1, WAITV(6));
  S1BODY(10, 1, 1, WAITV(6)); S1BODY(11, 1, 1, WAITV(6));
  S1BODY(12, 1, 1, WAITV(6)); S1BODY(13, 1, 1, WAITV(6));
  S1BODY(14, 1, 0, WAITV(4)); S1BODY(15, 0, 0, WAITV(0));
#undef S1BODY

  // per-wave reduce via LDS transpose (reuse this wave's vstage area)
  float* scr = (float*)&vstage[w][0][0];                 // 64x16 f32 = 4KB < 6KB
  int gg = (l & 31) >> 3, ii = (l & 7) | ((l >> 5) << 3);
  *(floatx4*)&scr[l * 16 + 0]  = (floatx4){s[0], s[1], s[2], s[3]};
  *(floatx4*)&scr[l * 16 + 4]  = (floatx4){s[4], s[5], s[6], s[7]};
  *(floatx4*)&scr[l * 16 + 8]  = (floatx4){s[8], s[9], s[10], s[11]};
  *(floatx4*)&scr[l * 16 + 12] = (floatx4){s[12], s[13], s[14], s[15]};
  asm volatile("s_waitcnt lgkmcnt(0)" ::: "memory");
  float sc = 0.f;
#pragma unroll
  for (int rr = 0; rr < 16; ++rr) sc += scr[(gg * 16 + rr) * 16 + ii];
  asm volatile("s_waitcnt lgkmcnt(0)" ::: "memory");
  *(floatx4*)&scr[l * 16 + 0]  = (floatx4){q[0], q[1], q[2], q[3]};
  *(floatx4*)&scr[l * 16 + 4]  = (floatx4){q[4], q[5], q[6], q[7]};
  *(floatx4*)&scr[l * 16 + 8]  = (floatx4){q[8], q[9], q[10], q[11]};
  *(floatx4*)&scr[l * 16 + 12] = (floatx4){q[12], q[13], q[14], q[15]};
  asm volatile("s_waitcnt lgkmcnt(0)" ::: "memory");
  float qc = 0.f;
#pragma unroll
  for (int rr = 0; rr < 16; ++rr) qc += scr[(gg * 16 + rr) * 16 + ii];
  rs[w][l] = sc; rq[w][l] = qc;
  __syncthreads();
  if (w == 0) {
    float ss = rs[0][l] + rs[1][l] + rs[2][l] + rs[3][l];
    float qq = rq[0][l] + rq[1][l] + rq[2][l] + rq[3][l];
    atomicAdd(&s1g[l], ss);
    atomicAdd(&q1g[l], qq);
  }
}

// ---------------- finalize BN stats -> affine (+ c/a) ----------------
__global__ void k_fin(const float* __restrict__ s, const float* __restrict__ q,
                      const float* __restrict__ g, const float* __restrict__ be,
                      float* __restrict__ a, float* __restrict__ c,
                      float* __restrict__ ca) {
  int o = threadIdx.x;
  float mean = s[o] / TOTF;
  float var = q[o] / TOTF - mean * mean;
  float av = g[o] / sqrtf(var + EPSV);
  float cv = be[o] - mean * av;
  a[o] = av;
  c[o] = cv;
  ca[o] = cv / av;
}

// -------- K4: async-gather -> relu1 -> MFMA(W2*a1) -> {BN2 stats, max->mx} --------
__global__ __launch_bounds__(256) void k_main(const unsigned short* __restrict__ Ub,
                                              const unsigned short* __restrict__ Vb,
                                              const int* __restrict__ idx,
                                              const float* __restrict__ a1,
                                              const float* __restrict__ c1a,
                                              const float* __restrict__ W2,
                                              const float* __restrict__ b2,
                                              float* __restrict__ s2,
                                              float* __restrict__ q2,
                                              unsigned short* __restrict__ Mxb) {
  __shared__ int idx_s[1024];
  __shared__ __align__(16) unsigned short vstage[4][3][1024];
  __shared__ __align__(16) unsigned short mx[64][64];
  __shared__ float sred[4][64], qred[4][64];
  __shared__ __align__(16) unsigned char lds_pad[18432];  // cap 2 blocks/CU
  int t = threadIdx.x;
  if (blockIdx.x > 0x7FFFFFF0u) ((volatile unsigned char*)lds_pad)[t] = 1;
  int l = t & 63, w = t >> 6;
  int g = l >> 4, r = l & 15;
  int b, n0; swz(blockIdx.x, b, n0);
  size_t bbase = (size_t)b * Nn, bn0 = bbase + n0, wbn = bn0 + w * 16;
  int g8 = g * 8;
  {
    const int* ip = idx + bn0 * 16;
    for (int i = t; i < 1024; i += 256) idx_s[i] = ip[i];
  }

  // B-frags: W2*a1, B[k=o][col=p]; lane: col=r, k=32hh+8g+i
  short8 bw[4][2];
#pragma unroll
  for (int tp = 0; tp < 4; ++tp)
#pragma unroll
    for (int hh = 0; hh < 2; ++hh)
#pragma unroll
      for (int i = 0; i < 8; ++i) {
        int o = 32 * hh + 8 * g + i;
        bw[tp][hh][i] = f2bfs(W2[(16 * tp + r) * 64 + o] * a1[o]);
      }
  float c1av[16];
#pragma unroll
  for (int i = 0; i < 8; ++i) {
    c1av[i] = c1a[g8 + i];
    c1av[8 + i] = c1a[32 + g8 + i];
  }
  float b2t[4];
#pragma unroll
  for (int tp = 0; tp < 4; ++tp) b2t[tp] = b2[16 * tp + r];

  __syncthreads();
  const unsigned short* Vbb = Vb + (bbase << 6);

  auto STAGE = [&](int pt, int slot) {
    int jn = idx_s[(w * 16 + pt) * 16 + r];
    const unsigned short* vp = Vbb + ((size_t)jn << 6) + g8;
    unsigned short* sl = &vstage[w][slot][0];
    gload_lds16(vp, sl);
    gload_lds16(vp + 32, sl + 512);
  };
  auto LOADU = [&](int pt, ushort8& lo, ushort8& hi) {
    const unsigned short* up = Ub + ((wbn + pt) << 6);
    lo = *(const ushort8*)(up + g8);
    hi = *(const ushort8*)(up + 32 + g8);
  };

  ushort8 uA_lo, uA_hi, uB_lo, uB_hi;
  STAGE(0, 0); LOADU(0, uA_lo, uA_hi); STAGE(1, 1);
  float sa[4] = {0.f, 0.f, 0.f, 0.f}, qa[4] = {0.f, 0.f, 0.f, 0.f};

#define MBODY(PT, DOLU, DOST, WAIT) { \
    if (DOLU) { if ((PT) & 1) LOADU((PT) + 1, uA_lo, uA_hi); else LOADU((PT) + 1, uB_lo, uB_hi); } \
    if (DOST) STAGE((PT) + 2, ((PT) + 2) % 3); \
    WAIT; \
    const unsigned short* sl = &vstage[w][(PT) % 3][0]; \
    ushort8 vlo = *(const ushort8*)(sl + l * 8); \
    ushort8 vhi = *(const ushort8*)(sl + 512 + l * 8); \
    ushort8 ulo = ((PT) & 1) ? uB_lo : uA_lo; \
    ushort8 uhi = ((PT) & 1) ? uB_hi : uA_hi; \
    float h[16]; \
    _Pragma("unroll") \
    for (int i = 0; i < 8; ++i) { \
      h[i] = bf2f(ulo[i]) + bf2f(vlo[i]); \
      h[8 + i] = bf2f(uhi[i]) + bf2f(vhi[i]); \
    } \
    _Pragma("unroll") \
    for (int i = 0; i < 16; ++i) h[i] = fmaxf(h[i] + c1av[i], 0.f); \
    short8 fa0, fa1; \
    _Pragma("unroll") \
    for (int i = 0; i < 8; ++i) { fa0[i] = f2bfs(h[i]); fa1[i] = f2bfs(h[8 + i]); } \
    _Pragma("unroll") \
    for (int tp = 0; tp < 4; ++tp) { \
      floatx4 acc = {b2t[tp], b2t[tp], b2t[tp], b2t[tp]}; \
      acc = __builtin_amdgcn_mfma_f32_16x16x32_bf16(fa0, bw[tp][0], acc, 0, 0, 0); \
      acc = __builtin_amdgcn_mfma_f32_16x16x32_bf16(fa1, bw[tp][1], acc, 0, 0, 0); \
      float mm = -3.4e38f; \
      _Pragma("unroll") \
      for (int rg = 0; rg < 4; ++rg) { \
        float h2 = acc[rg]; \
        sa[tp] += h2; qa[tp] += h2 * h2; \
        mm = fmaxf(mm, h2); \
      } \
      mm = fmaxf(mm, __shfl_xor(mm, 16)); \
      mm = fmaxf(mm, __shfl_xor(mm, 32)); \
      if (g == 0) mx[w * 16 + (PT)][tp * 16 + r] = f2bf(mm); \
    } }

  MBODY(0, 1, 1, WAITV(6));  MBODY(1, 1, 1, WAITV(6));
  MBODY(2, 1, 1, WAITV(6));  MBODY(3, 1, 1, WAITV(6));
  MBODY(4, 1, 1, WAITV(6));  MBODY(5, 1, 1, WAITV(6));
  MBODY(6, 1, 1, WAITV(6));  MBODY(7, 1, 1, WAITV(6));
  MBODY(8, 1, 1, WAITV(6));  MBODY(9, 1, 1, WAITV(6));
  MBODY(10, 1, 1, WAITV(6)); MBODY(11, 1, 1, WAITV(6));
  MBODY(12, 1, 1, WAITV(6)); MBODY(13, 1, 1, WAITV(6));
  MBODY(14, 1, 0, WAITV(4)); MBODY(15, 0, 0, WAITV(0));
#undef MBODY

  // stats reduce: over g (shfl), waves (LDS), then atomic
#pragma unroll
  for (int tp = 0; tp < 4; ++tp) {
    sa[tp] += __shfl_xor(sa[tp], 16); sa[tp] += __shfl_xor(sa[tp], 32);
    qa[tp] += __shfl_xor(qa[tp], 16); qa[tp] += __shfl_xor(qa[tp], 32);
  }
  if (g == 0) {
#pragma unroll
    for (int tp = 0; tp < 4; ++tp) { sred[w][tp * 16 + r] = sa[tp]; qred[w][tp * 16 + r] = qa[tp]; }
  }
  __syncthreads();
  if (w == 0) {
    float ss = sred[0][l] + sred[1][l] + sred[2][l] + sred[3][l];
    float qq = qred[0][l] + qred[1][l] + qred[2][l] + qred[3][l];
    atomicAdd(&s2[l], ss);
    atomicAdd(&q2[l], qq);
  }
  // bulk max store (coalesced 16B)
  const int4* msrc = (const int4*)mx;
  int4* mdst = (int4*)(Mxb + (bn0 << 6));
  for (int i = t; i < 512; i += 256) mdst[i] = msrc[i];
}

// -------- K6: BN2+relu on Mx(bf16), transposed write --------
__global__ __launch_bounds__(256) void k_out(const unsigned short* __restrict__ Mxb,
                                             const float* __restrict__ a2,
                                             const float* __restrict__ c2,
                                             float* __restrict__ out) {
  __shared__ float om[64][65];
  __shared__ float a2s[64], c2s[64];
  int t = threadIdx.x;
  int b, n0; swz(blockIdx.x, b, n0);
  if (t < 64) { a2s[t] = a2[t]; c2s[t] = c2[t]; }
  __syncthreads();
  const ushort4* src = (const ushort4*)(Mxb + ((size_t)b * Nn + n0) * 64);
  for (int i = t; i < 1024; i += 256) {
    ushort4 v4 = src[i];
    int ptl = i >> 4, p0 = (i & 15) * 4;
    unsigned short vv[4] = {v4.x, v4.y, v4.z, v4.w};
#pragma unroll
    for (int j = 0; j < 4; ++j) {
      int p = p0 + j;
      om[p][ptl] = fmaxf(fmaf(a2s[p], bf2f(vv[j]), c2s[p]), 0.f);
    }
  }
  __syncthreads();
  for (int i = t; i < 1024; i += 256) {
    int p = i >> 4, nn4 = (i & 15) * 4;
    float4 o4 = {om[p][nn4], om[p][nn4 + 1], om[p][nn4 + 2], om[p][nn4 + 3]};
    *(float4*)&out[((size_t)b * 64 + p) * Nn + n0 + nn4] = o4;
  }
}

extern "C" void kernel_launch(void* const* d_in, const int* in_sizes, int n_in,
                              void* d_out, int out_size, void* d_ws, size_t ws_size,
                              hipStream_t stream) {
  const float* x   = (const float*)d_in[0];
  const int*   idx = (const int*)d_in[1];
  const float* W1  = (const float*)d_in[2];
  const float* b1  = (const float*)d_in[3];
  const float* g1  = (const float*)d_in[4];
  const float* be1 = (const float*)d_in[5];
  const float* W2  = (const float*)d_in[6];
  const float* b2  = (const float*)d_in[7];
  const float* g2  = (const float*)d_in[8];
  const float* be2 = (const float*)d_in[9];
  float* out = (float*)d_out;

  unsigned short* Ub = (unsigned short*)d_ws;        // 16 MB
  unsigned short* Vb = Ub + (size_t)BN * 64;         // 16 MB
  float* st = (float*)(Vb + (size_t)BN * 64);
  float* s1  = st,       *q1 = st + 64,  *a1 = st + 128, *c1 = st + 192;
  float* s2  = st + 256, *q2 = st + 320, *a2 = st + 384, *c2 = st + 448;
  float* c1a = st + 512, *c2a = st + 576;
  unsigned short* Mxb = (unsigned short*)(st + 640); // 16 MB, [b][n][ch]

  hipError_t e = hipMemsetAsync(st, 0, 512 * sizeof(float), stream); (void)e;
  k_uv<<<2048, 256, 0, stream>>>(x, W1, b1, Ub, Vb);
  k_stats1<<<2048, 256, 0, stream>>>(Ub, Vb, idx, s1, q1);
  k_fin<<<1, 64, 0, stream>>>(s1, q1, g1, be1, a1, c1, c1a);
  k_main<<<2048, 256, 0, stream>>>(Ub, Vb, idx, a1, c1a, W2, b2, s2, q2, Mxb);
  k_fin<<<1, 64, 0, stream>>>(s2, q2, g2, be2, a2, c2, c2a);
  k_out<<<2048, 256, 0, stream>>>(Mxb, a2, c2, out);
}

// Round 13
// 245.621 us; speedup vs baseline: 1.5308x; 1.3120x over previous
//
#include <hip/hip_runtime.h>
#include <math.h>

// EdgeConv: B=4, C=64, N=32768, k=16, O=64
// U = (W1[:,:64]-W1[:,64:]) @ x + b1 ; V = W1[:,64:] @ x   (bf16-stored)
// h1 = U[n] + V[idx[n,k]] ; BN affine relu(a*h+c); layer2 bf16 MFMA 16x16x32.
// XCD swizzle: batch b -> XCD pair {2b,2b+1}; V (4MB bf16/batch) L2-resident.
// R12: re-anchor on the measured optimum (R4 kernels: 231us, k_main 96.8us,
// FETCH 49MB, VGPR 80, occ 27% -- below the L2-thrash cliff). Single delta:
// k_stats1 now clones k_main's async-gather pipeline (minus MFMA/stores),
// with the proven LDS-transpose wave reduce.

#define EPSV 1e-5f
constexpr int Cc = 64;
constexpr int Nn = 32768;
constexpr int BN = 131072;                     // B*N
constexpr float TOTF = 2097152.0f;             // B*N*k

typedef __attribute__((ext_vector_type(8))) short short8;
typedef __attribute__((ext_vector_type(8))) unsigned short ushort8;
typedef __attribute__((ext_vector_type(4))) float floatx4;

#define WAITV(N) asm volatile("s_waitcnt vmcnt(" #N ")" ::: "memory")

__device__ __forceinline__ unsigned short f2bf(float f) {
  __bf16 b = (__bf16)f;
  return __builtin_bit_cast(unsigned short, b);
}
__device__ __forceinline__ short f2bfs(float f) {
  __bf16 b = (__bf16)f;
  return __builtin_bit_cast(short, b);
}
__device__ __forceinline__ float bf2f(unsigned short u) {
  union { unsigned u; float f; } x; x.u = ((unsigned)u) << 16; return x.f;
}
__device__ __forceinline__ void gload_lds16(const void* g, void* l) {
  __builtin_amdgcn_global_load_lds(
      (const __attribute__((address_space(1))) unsigned int*)g,
      (__attribute__((address_space(3))) unsigned int*)l, 16, 0, 0);
}
// blockIdx -> (batch, 64-point chunk): batch pinned to XCD pair (bid%8)>>1
__device__ __forceinline__ void swz(int p, int& b, int& n0) {
  b = (p & 7) >> 1;
  n0 = (((p >> 3) << 1) | (p & 1)) << 6;
}

// ---------------- K1: U,V precompute (f32 compute, bf16 store) ----------------
__global__ __launch_bounds__(256) void k_uv(const float* __restrict__ x,
                                            const float* __restrict__ W1,
                                            const float* __restrict__ b1,
                                            unsigned short* __restrict__ Ub,
                                            unsigned short* __restrict__ Vb) {
  __shared__ __align__(16) float wdT[64][64];
  __shared__ __align__(16) float wbT[64][64];
  __shared__ __align__(16) float xs[64][64];
  int t = threadIdx.x;
  int b, n0; swz(blockIdx.x, b, n0);

  for (int i = t; i < 4096; i += 256) {
    int o = i & 63, c = i >> 6;
    float wa = W1[o * 128 + c];
    float wb = W1[o * 128 + 64 + c];
    wdT[c][o] = wa - wb;
    wbT[c][o] = wb;
  }
  const float* xb = x + (size_t)b * Cc * Nn + n0;
  for (int i = t; i < 4096; i += 256) {
    int c = i >> 6, p = i & 63;
    xs[c][p] = xb[(size_t)c * Nn + p];
  }
  __syncthreads();

  int lane = t & 63;
  int pg = t >> 6;
  int pbase = pg * 16;
  float bv = b1[lane];
  float u[16], v[16];
#pragma unroll
  for (int j = 0; j < 16; ++j) { u[j] = bv; v[j] = 0.f; }

  for (int c = 0; c < 64; ++c) {
    float wd = wdT[c][lane];
    float wb = wbT[c][lane];
#pragma unroll
    for (int j4 = 0; j4 < 4; ++j4) {
      float4 xq = *(const float4*)&xs[c][pbase + j4 * 4];
      u[j4 * 4 + 0] += wd * xq.x; v[j4 * 4 + 0] += wb * xq.x;
      u[j4 * 4 + 1] += wd * xq.y; v[j4 * 4 + 1] += wb * xq.y;
      u[j4 * 4 + 2] += wd * xq.z; v[j4 * 4 + 2] += wb * xq.z;
      u[j4 * 4 + 3] += wd * xq.w; v[j4 * 4 + 3] += wb * xq.w;
    }
  }
  size_t base = ((size_t)b * Nn + n0 + pbase) * 64 + lane;
#pragma unroll
  for (int j = 0; j < 16; ++j) {
    Ub[base + (size_t)j * 64] = f2bf(u[j]);
    Vb[base + (size_t)j * 64] = f2bf(v[j]);
  }
}

// ------- K2: BN1 stats -- k_main's async pipeline minus MFMA/stores -------
__global__ __launch_bounds__(256) void k_stats1(const unsigned short* __restrict__ Ub,
                                                const unsigned short* __restrict__ Vb,
                                                const int* __restrict__ idx,
                                                float* __restrict__ s1g,
                                                float* __restrict__ q1g) {
  __shared__ int idx_s[1024];
  __shared__ __align__(16) unsigned short vstage[4][4][1024];  // 32 KB
  __shared__ float rs[4][64], rq[4][64];
  int t = threadIdx.x;
  int l = t & 63, w = t >> 6;
  int g = l >> 4, r = l & 15;
  int b, n0; swz(blockIdx.x, b, n0);
  size_t bbase = (size_t)b * Nn, bn0 = bbase + n0, wbn = bn0 + w * 16;
  int g8 = g * 8;
  {
    const int* ip = idx + bn0 * 16;
    for (int i = t; i < 1024; i += 256) idx_s[i] = ip[i];
  }
  __syncthreads();
  const unsigned short* Vbb = Vb + (bbase << 6);

  auto STAGE = [&](int pt) {
    int jn = idx_s[(w * 16 + pt) * 16 + r];
    const unsigned short* vp = Vbb + ((size_t)jn << 6) + g8;
    unsigned short* sl = &vstage[w][pt & 3][0];
    gload_lds16(vp, sl);
    gload_lds16(vp + 32, sl + 512);
  };
  auto LOADU = [&](int pt, ushort8& lo, ushort8& hi) {
    const unsigned short* up = Ub + ((wbn + pt) << 6);
    lo = *(const ushort8*)(up + g8);
    hi = *(const ushort8*)(up + 32 + g8);
  };

  ushort8 uA_lo, uA_hi, uB_lo, uB_hi;
  STAGE(0); LOADU(0, uA_lo, uA_hi);
  STAGE(1); LOADU(1, uB_lo, uB_hi);

  float s[16], q[16];
#pragma unroll
  for (int i = 0; i < 16; ++i) { s[i] = 0.f; q[i] = 0.f; }

#pragma unroll 2
  for (int pt = 0; pt < 16; ++pt) {
    ushort8 nlo, nhi;
    bool pre = (pt + 2 < 16);
    if (pre) { STAGE(pt + 2); LOADU(pt + 2, nlo, nhi); }
    else { nlo = uB_lo; nhi = uB_hi; }
    if (pt < 14)      WAITV(8);
    else if (pt < 15) WAITV(4);
    else              WAITV(0);
    const unsigned short* sl = &vstage[w][pt & 3][0];
    ushort8 vlo = *(const ushort8*)(sl + l * 8);
    ushort8 vhi = *(const ushort8*)(sl + 512 + l * 8);
    ushort8 ulo = (pt & 1) ? uB_lo : uA_lo;
    ushort8 uhi = (pt & 1) ? uB_hi : uA_hi;
#pragma unroll
    for (int i = 0; i < 8; ++i) {
      float h0 = bf2f(ulo[i]) + bf2f(vlo[i]);
      float h1 = bf2f(uhi[i]) + bf2f(vhi[i]);
      s[i] += h0; q[i] += h0 * h0;
      s[8 + i] += h1; q[8 + i] += h1 * h1;
    }
    if ((pt & 1) == 0) { uA_lo = nlo; uA_hi = nhi; }
    else               { uB_lo = nlo; uB_hi = nhi; }
  }

  // per-wave reduce via LDS transpose (scratch: this wave's vstage, 8KB >= 4KB)
  float* scr = (float*)&vstage[w][0][0];
  int gg = (l & 31) >> 3, ii = (l & 7) | ((l >> 5) << 3);
  *(floatx4*)&scr[l * 16 + 0]  = (floatx4){s[0], s[1], s[2], s[3]};
  *(floatx4*)&scr[l * 16 + 4]  = (floatx4){s[4], s[5], s[6], s[7]};
  *(floatx4*)&scr[l * 16 + 8]  = (floatx4){s[8], s[9], s[10], s[11]};
  *(floatx4*)&scr[l * 16 + 12] = (floatx4){s[12], s[13], s[14], s[15]};
  asm volatile("s_waitcnt lgkmcnt(0)" ::: "memory");
  float sc = 0.f;
#pragma unroll
  for (int rr = 0; rr < 16; ++rr) sc += scr[(gg * 16 + rr) * 16 + ii];
  asm volatile("s_waitcnt lgkmcnt(0)" ::: "memory");
  *(floatx4*)&scr[l * 16 + 0]  = (floatx4){q[0], q[1], q[2], q[3]};
  *(floatx4*)&scr[l * 16 + 4]  = (floatx4){q[4], q[5], q[6], q[7]};
  *(floatx4*)&scr[l * 16 + 8]  = (floatx4){q[8], q[9], q[10], q[11]};
  *(floatx4*)&scr[l * 16 + 12] = (floatx4){q[12], q[13], q[14], q[15]};
  asm volatile("s_waitcnt lgkmcnt(0)" ::: "memory");
  float qc = 0.f;
#pragma unroll
  for (int rr = 0; rr < 16; ++rr) qc += scr[(gg * 16 + rr) * 16 + ii];
  rs[w][l] = sc; rq[w][l] = qc;
  __syncthreads();
  if (w == 0) {
    float ss = rs[0][l] + rs[1][l] + rs[2][l] + rs[3][l];
    float qq = rq[0][l] + rq[1][l] + rq[2][l] + rq[3][l];
    atomicAdd(&s1g[l], ss);
    atomicAdd(&q1g[l], qq);
  }
}

// ---------------- finalize BN stats -> affine ----------------
__global__ void k_fin(const float* __restrict__ s, const float* __restrict__ q,
                      const float* __restrict__ g, const float* __restrict__ be,
                      float* __restrict__ a, float* __restrict__ c) {
  int o = threadIdx.x;
  float mean = s[o] / TOTF;
  float var = q[o] / TOTF - mean * mean;
  float av = g[o] / sqrtf(var + EPSV);
  a[o] = av;
  c[o] = be[o] - mean * av;
}

// -------- K4: async-gather -> BN1+relu -> MFMA -> {BN2 stats, max -> Mxb} --------
__global__ __launch_bounds__(256) void k_main(const unsigned short* __restrict__ Ub,
                                              const unsigned short* __restrict__ Vb,
                                              const int* __restrict__ idx,
                                              const float* __restrict__ a1,
                                              const float* __restrict__ c1,
                                              const float* __restrict__ W2,
                                              const float* __restrict__ b2,
                                              float* __restrict__ s2,
                                              float* __restrict__ q2,
                                              unsigned short* __restrict__ Mxb) {
  __shared__ int idx_s[1024];
  __shared__ float sred[4][64], qred[4][64];
  __shared__ __align__(16) unsigned short vstage[4][4][1024];  // 32 KB
  int t = threadIdx.x;
  int l = t & 63, w = t >> 6;
  int g = l >> 4, r = l & 15;
  int b, n0; swz(blockIdx.x, b, n0);
  size_t bbase = (size_t)b * Nn;
  size_t bn0 = bbase + n0;
  size_t wbn = bn0 + w * 16;
  int g8 = g * 8;

  {
    const int* ip = idx + bn0 * 16;
    for (int i = t; i < 1024; i += 256) idx_s[i] = ip[i];
  }

  short8 bw[4][2];
#pragma unroll
  for (int tp = 0; tp < 4; ++tp)
#pragma unroll
    for (int hh = 0; hh < 2; ++hh)
#pragma unroll
      for (int i = 0; i < 8; ++i)
        bw[tp][hh][i] = f2bfs(W2[(16 * tp + r) * 64 + 32 * hh + 8 * g + i]);

  float a1v[16], c1v[16];
#pragma unroll
  for (int i = 0; i < 8; ++i) {
    a1v[i] = a1[8 * g + i];          c1v[i] = c1[8 * g + i];
    a1v[8 + i] = a1[32 + 8 * g + i]; c1v[8 + i] = c1[32 + 8 * g + i];
  }
  float b2t[4];
#pragma unroll
  for (int tp = 0; tp < 4; ++tp) b2t[tp] = b2[16 * tp + r];

  __syncthreads();
  const unsigned short* Vbb = Vb + (bbase << 6);

  auto STAGE = [&](int pt) {
    int jn = idx_s[(w * 16 + pt) * 16 + r];
    const unsigned short* vp = Vbb + ((size_t)jn << 6) + g8;
    unsigned short* sl = &vstage[w][pt & 3][0];
    gload_lds16(vp, sl);
    gload_lds16(vp + 32, sl + 512);
  };
  auto LOADU = [&](int pt, ushort8& lo, ushort8& hi) {
    const unsigned short* up = Ub + ((wbn + pt) << 6);
    lo = *(const ushort8*)(up + g8);
    hi = *(const ushort8*)(up + 32 + g8);
  };

  ushort8 uA_lo, uA_hi, uB_lo, uB_hi;
  STAGE(0); LOADU(0, uA_lo, uA_hi);
  STAGE(1); LOADU(1, uB_lo, uB_hi);

  float sa[4] = {0.f, 0.f, 0.f, 0.f}, qa[4] = {0.f, 0.f, 0.f, 0.f};

#pragma unroll 2
  for (int pt = 0; pt < 16; ++pt) {
    ushort8 nlo, nhi;
    bool pre = (pt + 2 < 16);
    if (pre) { STAGE(pt + 2); LOADU(pt + 2, nlo, nhi); }
    else { nlo = uB_lo; nhi = uB_hi; }
    if (pt < 14)      WAITV(8);
    else if (pt < 15) WAITV(4);
    else              WAITV(0);
    const unsigned short* sl = &vstage[w][pt & 3][0];
    ushort8 v_lo = *(const ushort8*)(sl + l * 8);
    ushort8 v_hi = *(const ushort8*)(sl + 512 + l * 8);
    ushort8 u_lo = (pt & 1) ? uB_lo : uA_lo;
    ushort8 u_hi = (pt & 1) ? uB_hi : uA_hi;

    float h[16];
#pragma unroll
    for (int i = 0; i < 8; ++i) {
      h[i]     = bf2f(u_lo[i]) + bf2f(v_lo[i]);
      h[8 + i] = bf2f(u_hi[i]) + bf2f(v_hi[i]);
    }
#pragma unroll
    for (int i = 0; i < 16; ++i) h[i] = fmaxf(fmaf(a1v[i], h[i], c1v[i]), 0.f);
    short8 fa0, fa1;
#pragma unroll
    for (int i = 0; i < 8; ++i) { fa0[i] = f2bfs(h[i]); fa1[i] = f2bfs(h[8 + i]); }

    float m0, m1, m2, m3;
#pragma unroll
    for (int tp = 0; tp < 4; ++tp) {
      floatx4 acc = {b2t[tp], b2t[tp], b2t[tp], b2t[tp]};
      acc = __builtin_amdgcn_mfma_f32_16x16x32_bf16(fa0, bw[tp][0], acc, 0, 0, 0);
      acc = __builtin_amdgcn_mfma_f32_16x16x32_bf16(fa1, bw[tp][1], acc, 0, 0, 0);
      float mm = -3.4e38f;
#pragma unroll
      for (int rg = 0; rg < 4; ++rg) {
        float h2 = acc[rg];
        sa[tp] += h2; qa[tp] += h2 * h2;
        mm = fmaxf(mm, h2);
      }
      mm = fmaxf(mm, __shfl_xor(mm, 16));
      mm = fmaxf(mm, __shfl_xor(mm, 32));
      if (tp == 0) m0 = mm; else if (tp == 1) m1 = mm;
      else if (tp == 2) m2 = mm; else m3 = mm;
    }
    // lane (g,r) writes channel g*16+r <- max for tp==g
    float mv = (g == 0) ? m0 : (g == 1) ? m1 : (g == 2) ? m2 : m3;
    Mxb[((wbn + pt) << 6) + l] = f2bf(mv);

    if ((pt & 1) == 0) { uA_lo = nlo; uA_hi = nhi; }
    else               { uB_lo = nlo; uB_hi = nhi; }
  }

#pragma unroll
  for (int tp = 0; tp < 4; ++tp) {
    sa[tp] += __shfl_xor(sa[tp], 16); sa[tp] += __shfl_xor(sa[tp], 32);
    qa[tp] += __shfl_xor(qa[tp], 16); qa[tp] += __shfl_xor(qa[tp], 32);
  }
  if (g == 0) {
#pragma unroll
    for (int tp = 0; tp < 4; ++tp) { sred[w][tp * 16 + r] = sa[tp]; qred[w][tp * 16 + r] = qa[tp]; }
  }
  __syncthreads();
  if (w == 0) {
    float s = sred[0][l] + sred[1][l] + sred[2][l] + sred[3][l];
    float q = qred[0][l] + qred[1][l] + qred[2][l] + qred[3][l];
    atomicAdd(&s2[l], s);
    atomicAdd(&q2[l], q);
  }
}

// -------- K6: BN2+relu on Mxb (point-major bf16), transposed write --------
__global__ __launch_bounds__(256) void k_out(const unsigned short* __restrict__ Mxb,
                                             const float* __restrict__ a2,
                                             const float* __restrict__ c2,
                                             float* __restrict__ out) {
  __shared__ float om[64][65];
  __shared__ float a2s[64], c2s[64];
  int t = threadIdx.x;
  int b, n0; swz(blockIdx.x, b, n0);
  if (t < 64) { a2s[t] = a2[t]; c2s[t] = c2[t]; }
  __syncthreads();
  const ushort4* src = (const ushort4*)(Mxb + ((size_t)b * Nn + n0) * 64);
  for (int i = t; i < 1024; i += 256) {
    ushort4 v4 = src[i];
    int ptl = i >> 4, p0 = (i & 15) * 4;
    unsigned short vv[4] = {v4.x, v4.y, v4.z, v4.w};
#pragma unroll
    for (int j = 0; j < 4; ++j) {
      int p = p0 + j;
      om[p][ptl] = fmaxf(fmaf(a2s[p], bf2f(vv[j]), c2s[p]), 0.f);
    }
  }
  __syncthreads();
  for (int i = t; i < 1024; i += 256) {
    int p = i >> 4, nn4 = (i & 15) * 4;
    float4 o4 = {om[p][nn4], om[p][nn4 + 1], om[p][nn4 + 2], om[p][nn4 + 3]};
    *(float4*)&out[((size_t)b * 64 + p) * Nn + n0 + nn4] = o4;
  }
}

extern "C" void kernel_launch(void* const* d_in, const int* in_sizes, int n_in,
                              void* d_out, int out_size, void* d_ws, size_t ws_size,
                              hipStream_t stream) {
  const float* x   = (const float*)d_in[0];
  const int*   idx = (const int*)d_in[1];
  const float* W1  = (const float*)d_in[2];
  const float* b1  = (const float*)d_in[3];
  const float* g1  = (const float*)d_in[4];
  const float* be1 = (const float*)d_in[5];
  const float* W2  = (const float*)d_in[6];
  const float* b2  = (const float*)d_in[7];
  const float* g2  = (const float*)d_in[8];
  const float* be2 = (const float*)d_in[9];
  float* out = (float*)d_out;

  unsigned short* Ub = (unsigned short*)d_ws;        // 16 MB
  unsigned short* Vb = Ub + (size_t)BN * 64;         // 16 MB
  float* st = (float*)(Vb + (size_t)BN * 64);
  float* s1 = st,       *q1 = st + 64,  *a1 = st + 128, *c1 = st + 192;
  float* s2 = st + 256, *q2 = st + 320, *a2 = st + 384, *c2 = st + 448;
  unsigned short* Mxb = (unsigned short*)(st + 512); // 16 MB, [b][n][ch]

  hipError_t e = hipMemsetAsync(st, 0, 512 * sizeof(float), stream); (void)e;
  k_uv<<<2048, 256, 0, stream>>>(x, W1, b1, Ub, Vb);
  k_stats1<<<2048, 256, 0, stream>>>(Ub, Vb, idx, s1, q1);
  k_fin<<<1, 64, 0, stream>>>(s1, q1, g1, be1, a1, c1);
  k_main<<<2048, 256, 0, stream>>>(Ub, Vb, idx, a1, c1, W2, b2, s2, q2, Mxb);
  k_fin<<<1, 64, 0, stream>>>(s2, q2, g2, be2, a2, c2);
  k_out<<<2048, 256, 0, stream>>>(Mxb, a2, c2, out);
}